// Round 28
// baseline (535.564 us; speedup 1.0000x reference)
//
#include <hip/hip_runtime.h>
#include <hip/hip_bf16.h>

// ---------------- problem constants ----------------
constexpr int B_   = 8;
constexpr int D_   = 512;
constexpr int L0_  = 1024;
constexpr int L_   = 1025;          // L0 + cls
constexpr int H_   = 8;
constexpr int DH_  = 64;
constexpr int DFF_ = 2048;
constexpr int NLAYER_ = 2;
constexpr int M_   = B_ * L_;       // 8200 rows
constexpr int LP_  = 1088;          // padded L for Vt (17*64)
constexpr int NQT_ = 9;             // ceil(L/128) attn q-tiles
constexpr int NSPLIT_ = 2;          // K-range partitions (flash-decoding)
constexpr float EPS_   = 1e-6f;
// 0.125 * log2(e): scores produced directly in log2 domain (exp2 softmax)
constexpr float QSCALE_ = 0.18033688011112042f;

#define DEV_INLINE __device__ __forceinline__

typedef __attribute__((ext_vector_type(8)))  __bf16 bf16x8;
typedef __attribute__((ext_vector_type(4)))  __bf16 bf16x4;
typedef __attribute__((ext_vector_type(4)))  float  f32x4;
typedef __attribute__((ext_vector_type(16))) float  f32x16;
typedef __attribute__((ext_vector_type(4)))  unsigned int u32x4;
typedef __attribute__((ext_vector_type(2)))  unsigned int u32x2;

union U4 { uint32_t u[4]; bf16x8 f; };

DEV_INLINE float gelu_exact(float x) {
    return 0.5f * x * (1.f + erff(x * 0.70710678118654752f));
}

DEV_INLINE uint16_t bfbits(float v) {
    __bf16 h = (__bf16)v;
    return __builtin_bit_cast(uint16_t, h);
}
DEV_INLINE uint32_t pk2f(float a, float b) {
    return (uint32_t)bfbits(a) | ((uint32_t)bfbits(b) << 16);
}
DEV_INLINE float bf2f(uint32_t bits16) {           // low 16 bits = bf16
    uint32_t u = bits16 << 16;
    return __builtin_bit_cast(float, u);
}
DEV_INLINE uint32_t b32f(float f) { return __builtin_bit_cast(uint32_t, f); }
DEV_INLINE float f32b(uint32_t u) { return __builtin_bit_cast(float, u); }

// async global->LDS DMA, 16B per lane; LDS dest = wave-uniform base + lane*16
DEV_INLINE void gload16(const __bf16* g, __bf16* l) {
    __builtin_amdgcn_global_load_lds(
        (const __attribute__((address_space(1))) void*)g,
        (__attribute__((address_space(3))) void*)l,
        16, 0, 0);
}

// ---------------- fp32 -> bf16 ----------------
__global__ __launch_bounds__(256) void tobf16_kernel(
    const float* __restrict__ src, __bf16* __restrict__ dst, int n4) {
    int i = blockIdx.x * 256 + threadIdx.x;
    if (i >= n4) return;
    float4 v = *(const float4*)&src[i * 4];
    bf16x4 h;
    h[0] = (__bf16)v.x; h[1] = (__bf16)v.y;
    h[2] = (__bf16)v.z; h[3] = (__bf16)v.w;
    *(bf16x4*)&dst[i * 4] = h;
}

// ---------------- zero Vt pad tokens (l = L_..LP_-1), bf16 ----------------
// CRITICAL: pad tokens feed PV MFMA with P=0; garbage bits can alias bf16
// Inf/NaN and 0*Inf = NaN (R10 failure). Must be zeroed every layer.
__global__ __launch_bounds__(256) void zero_vt_pad_kernel(__bf16* __restrict__ Vt) {
    constexpr int PAD = LP_ - L_;                 // 63
    int idx = blockIdx.x * 256 + threadIdx.x;
    int total = B_ * H_ * DH_ * PAD;
    if (idx >= total) return;
    int row = idx / PAD;
    int c   = idx - row * PAD;
    Vt[(size_t)row * LP_ + L_ + c] = (__bf16)0.f;
}

// ---------------- build x1/x2 ----------------
__global__ __launch_bounds__(256) void write_cls_kernel(
    const float* __restrict__ cls, float* __restrict__ X1, float* __restrict__ X2) {
    int idx = blockIdx.x * 256 + threadIdx.x;
    int b = idx >> 9;
    int d = idx & 511;
    float v = cls[d];
    X1[(size_t)b * L_ * D_ + d] = v;
    X2[(size_t)b * L_ * D_ + d] = v;
}

// embed [B, D, L0] -> X rows 1..L0
__global__ __launch_bounds__(256) void transpose_embed_kernel(
    const float* __restrict__ e, float* __restrict__ X) {
    __shared__ float tile[32][33];
    int b  = blockIdx.z;
    int i0 = blockIdx.x * 32;
    int d0 = blockIdx.y * 32;
    int tx = threadIdx.x;
    int ty = threadIdx.y;
#pragma unroll
    for (int j = 0; j < 32; j += 8)
        tile[ty + j][tx] = e[((size_t)b * D_ + d0 + ty + j) * L0_ + i0 + tx];
    __syncthreads();
#pragma unroll
    for (int j = 0; j < 32; j += 8)
        X[((size_t)b * L_ + 1 + i0 + ty + j) * D_ + d0 + tx] = tile[tx][ty + j];
}

// ---------------- pure bf16 MFMA GEMM, BK=64, double-buffered gload_lds ----------------
// 2-phase pipeline (T3 minimum recipe): issue STAGE(buf^1, t+1) BEFORE compute(buf),
// ONE barrier per K-step -- DMA latency hides under MFMA. Bit-identical math.
// OUTMODE: 0 = fp32, 2 = bf16.
template <bool GELU, int OUTMODE>
__global__ __launch_bounds__(256) void gemm_mfma_kernel(
    const __bf16* __restrict__ A, const __bf16* __restrict__ Wh,
    const float* __restrict__ bias, float* __restrict__ C,
    __bf16* __restrict__ Ch, int M, int N, int K, float oscale) {
    constexpr int BM = 128, BN = 64, BK = 64;
    __shared__ alignas(16) __bf16 Ahs[2][BM * BK];   // 2 x 16 KB
    __shared__ alignas(16) __bf16 Bhs[2][BN * BK];   // 2 x 8 KB

    const int GM = (M + BM - 1) / BM;
    const int nwg = gridDim.x;
    int bid = blockIdx.x;
    {
        int q = nwg >> 3, r = nwg & 7;
        int xcd = bid & 7, pos = bid >> 3;
        bid = (xcd < r) ? xcd * (q + 1) + pos
                        : r * (q + 1) + (xcd - r) * q + pos;
    }
    const int bn = bid / GM;
    const int bm = bid % GM;
    const int m0 = bm * BM;
    const int n0 = bn * BN;

    const int tid  = threadIdx.x;
    const int lane = tid & 63;
    const int wv   = tid >> 6;
    const int wr   = wv >> 1;
    const int wc   = wv & 1;
    const int fr   = lane & 15;
    const int fq   = lane >> 4;
    const int fq8  = fq * 8;
    const int mb   = wr * 64;
    const int nb   = wc * 32;
    const int swz  = (fr & 7) << 3;               // read-side col XOR (elements)

    // staging source offsets (pre-swizzled col within 64-elem slice)
    const int srcColE = (((lane & 7) ^ (lane >> 3)) << 3);
    size_t aSrc[4];
#pragma unroll
    for (int j = 0; j < 4; ++j) {
        int row = (wv * 4 + j) * 8 + (lane >> 3);
        int ar = m0 + row; if (ar > M - 1) ar = M - 1;
        aSrc[j] = (size_t)ar * K + srcColE;
    }
    size_t bSrc[2];
#pragma unroll
    for (int j = 0; j < 2; ++j) {
        int row = (wv * 2 + j) * 8 + (lane >> 3);
        bSrc[j] = (size_t)(n0 + row) * K + srcColE;
    }

    f32x4 acc[4][2];
#pragma unroll
    for (int i = 0; i < 4; ++i)
#pragma unroll
        for (int j = 0; j < 2; ++j) acc[i][j] = (f32x4){0.f, 0.f, 0.f, 0.f};

    const int nk = K / BK;
    // prologue: stage tile 0 into buf 0
#pragma unroll
    for (int j = 0; j < 4; ++j) gload16(A + aSrc[j], &Ahs[0][(wv * 4 + j) * 512]);
#pragma unroll
    for (int j = 0; j < 2; ++j) gload16(Wh + bSrc[j], &Bhs[0][(wv * 2 + j) * 512]);

    int cur = 0;
    for (int kt = 0; kt < nk; ++kt) {
        __syncthreads();   // buf[cur] DMA landed; buf[cur^1] free to overwrite

        if (kt + 1 < nk) {
            int k0 = (kt + 1) * BK;
#pragma unroll
            for (int j = 0; j < 4; ++j) gload16(A + aSrc[j] + k0, &Ahs[cur ^ 1][(wv * 4 + j) * 512]);
#pragma unroll
            for (int j = 0; j < 2; ++j) gload16(Wh + bSrc[j] + k0, &Bhs[cur ^ 1][(wv * 2 + j) * 512]);
        }

#pragma unroll
        for (int ks = 0; ks < 2; ++ks) {
            bf16x8 ah[4], bh[2];
#pragma unroll
            for (int i = 0; i < 4; ++i)
                ah[i] = *(bf16x8*)&Ahs[cur][(mb + i * 16 + fr) * 64 + ((ks * 32 + fq8) ^ swz)];
#pragma unroll
            for (int j = 0; j < 2; ++j)
                bh[j] = *(bf16x8*)&Bhs[cur][(nb + j * 16 + fr) * 64 + ((ks * 32 + fq8) ^ swz)];
#pragma unroll
            for (int i = 0; i < 4; ++i)
#pragma unroll
                for (int j = 0; j < 2; ++j)
                    acc[i][j] = __builtin_amdgcn_mfma_f32_16x16x32_bf16(ah[i], bh[j], acc[i][j], 0, 0, 0);
        }
        cur ^= 1;
    }

    const int ccol0 = n0 + nb + fr;
    const float b0 = bias[ccol0];
    const float b1 = bias[ccol0 + 16];
#pragma unroll
    for (int i = 0; i < 4; ++i) {
#pragma unroll
        for (int r = 0; r < 4; ++r) {
            int row = m0 + mb + i * 16 + fq * 4 + r;
            if (row < M) {
                float v0 = acc[i][0][r] + b0;
                float v1 = acc[i][1][r] + b1;
                if (GELU) { v0 = gelu_exact(v0); v1 = gelu_exact(v1); }
                v0 *= oscale;
                v1 *= oscale;
                if (OUTMODE == 2) {
                    Ch[(size_t)row * N + ccol0]      = (__bf16)v0;
                    Ch[(size_t)row * N + ccol0 + 16] = (__bf16)v1;
                } else {
                    C[(size_t)row * N + ccol0]      = v0;
                    C[(size_t)row * N + ccol0 + 16] = v1;
                }
            }
        }
    }
}

// ---------------- fused K+V GEMM, double-buffered gload_lds (V stored transposed) ----------------
__global__ __launch_bounds__(256) void gemm_kv_kernel(
    const __bf16* __restrict__ A, const __bf16* __restrict__ Wh,
    const float* __restrict__ biasK, const float* __restrict__ biasV,
    __bf16* __restrict__ Kb, __bf16* __restrict__ Vt) {
    constexpr int BM = 128, BN = 64, BK = 64, K = 512;
    __shared__ alignas(16) __bf16 Ahs[2][BM * BK];
    __shared__ alignas(16) __bf16 Bhs[2][BN * BK];

    const int GM = (M_ + BM - 1) / BM;
    const int nwg = gridDim.x;
    int bid = blockIdx.x;
    {
        int q = nwg >> 3, r = nwg & 7;
        int xcd = bid & 7, pos = bid >> 3;
        bid = (xcd < r) ? xcd * (q + 1) + pos
                        : r * (q + 1) + (xcd - r) * q + pos;
    }
    const int bn = bid / GM;
    const int bm = bid % GM;
    const int m0 = bm * BM;
    const int n0 = bn * BN;

    const int tid  = threadIdx.x;
    const int lane = tid & 63;
    const int wv   = tid >> 6;
    const int wr   = wv >> 1;
    const int wc   = wv & 1;
    const int fr   = lane & 15;
    const int fq   = lane >> 4;
    const int fq8  = fq * 8;
    const int mb   = wr * 64;
    const int nb   = wc * 32;
    const int swz  = (fr & 7) << 3;

    const int srcColE = (((lane & 7) ^ (lane >> 3)) << 3);
    size_t aSrc[4];
#pragma unroll
    for (int j = 0; j < 4; ++j) {
        int row = (wv * 4 + j) * 8 + (lane >> 3);
        int ar = m0 + row; if (ar > M_ - 1) ar = M_ - 1;
        aSrc[j] = (size_t)ar * K + srcColE;
    }
    size_t bSrc[2];
#pragma unroll
    for (int j = 0; j < 2; ++j) {
        int row = (wv * 2 + j) * 8 + (lane >> 3);
        bSrc[j] = (size_t)(n0 + row) * K + srcColE;
    }

    f32x4 acc[4][2];
#pragma unroll
    for (int i = 0; i < 4; ++i)
#pragma unroll
        for (int j = 0; j < 2; ++j) acc[i][j] = (f32x4){0.f, 0.f, 0.f, 0.f};

    const int nk = K / BK;
#pragma unroll
    for (int j = 0; j < 4; ++j) gload16(A + aSrc[j], &Ahs[0][(wv * 4 + j) * 512]);
#pragma unroll
    for (int j = 0; j < 2; ++j) gload16(Wh + bSrc[j], &Bhs[0][(wv * 2 + j) * 512]);

    int cur = 0;
    for (int kt = 0; kt < nk; ++kt) {
        __syncthreads();

        if (kt + 1 < nk) {
            int k0 = (kt + 1) * BK;
#pragma unroll
            for (int j = 0; j < 4; ++j) gload16(A + aSrc[j] + k0, &Ahs[cur ^ 1][(wv * 4 + j) * 512]);
#pragma unroll
            for (int j = 0; j < 2; ++j) gload16(Wh + bSrc[j] + k0, &Bhs[cur ^ 1][(wv * 2 + j) * 512]);
        }

#pragma unroll
        for (int ks = 0; ks < 2; ++ks) {
            bf16x8 ah[4], bh[2];
#pragma unroll
            for (int i = 0; i < 4; ++i)
                ah[i] = *(bf16x8*)&Ahs[cur][(mb + i * 16 + fr) * 64 + ((ks * 32 + fq8) ^ swz)];
#pragma unroll
            for (int j = 0; j < 2; ++j)
                bh[j] = *(bf16x8*)&Bhs[cur][(nb + j * 16 + fr) * 64 + ((ks * 32 + fq8) ^ swz)];
#pragma unroll
            for (int i = 0; i < 4; ++i)
#pragma unroll
                for (int j = 0; j < 2; ++j)
                    acc[i][j] = __builtin_amdgcn_mfma_f32_16x16x32_bf16(ah[i], bh[j], acc[i][j], 0, 0, 0);
        }
        cur ^= 1;
    }

    const int ccol0 = n0 + nb + fr;
    if (n0 < 512) {
        const float b0 = biasK[ccol0];
        const float b1 = biasK[ccol0 + 16];
#pragma unroll
        for (int i = 0; i < 4; ++i) {
#pragma unroll
            for (int r = 0; r < 4; ++r) {
                int row = m0 + mb + i * 16 + fq * 4 + r;
                if (row < M_) {
                    Kb[(size_t)row * 512 + ccol0]      = (__bf16)(acc[i][0][r] + b0);
                    Kb[(size_t)row * 512 + ccol0 + 16] = (__bf16)(acc[i][1][r] + b1);
                }
            }
        }
    } else {
        const int cv = ccol0 - 512;
        const int h2 = cv >> 6, d2 = cv & 63;
        const float b0 = biasV[cv];
        const float b1 = biasV[cv + 16];
#pragma unroll
        for (int i = 0; i < 4; ++i) {
#pragma unroll
            for (int r = 0; r < 4; ++r) {
                int row = m0 + mb + i * 16 + fq * 4 + r;
                if (row < M_) {
                    int b2 = row / L_;
                    int l2 = row - b2 * L_;
                    size_t vb = (size_t)(b2 * H_ + h2) * DH_ * LP_;
                    Vt[vb + (size_t)d2 * LP_ + l2]        = (__bf16)(acc[i][0][r] + b0);
                    Vt[vb + (size_t)(d2 + 16) * LP_ + l2] = (__bf16)(acc[i][1][r] + b1);
                }
            }
        }
    }
}

// ---------------- MFMA flash attention: 32x32 swapped form, exp2 softmax ----------------
// Scores arrive in log2 domain (QSCALE_ folded into Q). All lane^32 exchanges
// via permlane32_swap (VALU pipe, zero selects). Tree reductions; setprio on MFMA.
__global__ __launch_bounds__(256) void attn_mfma_kernel(
    const __bf16* __restrict__ Qb, const __bf16* __restrict__ Kb,
    const __bf16* __restrict__ Vtb, __bf16* __restrict__ Opart,
    float* __restrict__ ml) {
    constexpr int LDP = 72;                   // bf16 row stride (144B)
    constexpr int NT = (L_ + 63) / 64;        // 17
    __shared__ alignas(16) __bf16 Kls[64][LDP];
    __shared__ alignas(16) __bf16 Vls[64][LDP];

    const int tid  = threadIdx.x;
    const int lane = tid & 63;
    const int wv   = tid >> 6;
    const int la   = lane & 31;               // q column (and k/d row for frags)
    const int hl   = lane >> 5;               // lane half

    int bid = blockIdx.x;
    int swz = (bid & 7) * (NSPLIT_ * NQT_ * H_ * B_ / 8) + (bid >> 3);
    const int s   = swz / (NQT_ * H_ * B_);
    int rem = swz - s * (NQT_ * H_ * B_);
    const int qt = rem % NQT_;
    const int bh = rem / NQT_;
    const int h = bh & 7, b = bh >> 3;
    const int q0 = qt * 128 + wv * 32;
    const int T0 = (NT * s) / NSPLIT_;
    const int T1 = (NT * (s + 1)) / NSPLIT_;
    const size_t obase = (size_t)b * L_ * D_ + h * DH_;

    bf16x8 bq[4];
    {
        int gq = q0 + la; if (gq > L_ - 1) gq = L_ - 1;
        const __bf16* qrow = Qb + (size_t)(b * L_ + gq) * D_ + h * DH_;
#pragma unroll
        for (int c = 0; c < 4; ++c)
            bq[c] = *(const bf16x8*)&qrow[c * 16 + hl * 8];
    }

    float m = -1e30f, lsum = 0.f;
    f32x16 oT0, oT1;
#pragma unroll
    for (int r = 0; r < 16; ++r) { oT0[r] = 0.f; oT1[r] = 0.f; }

    const int sr  = tid >> 2;
    const int scb = (tid & 3) * 8;
    const size_t kRowBase = (size_t)(b * L_) * D_ + h * DH_ + scb;
    const size_t vRowBase = ((size_t)bh * DH_ + sr) * LP_ + scb;

    u32x4 kR[2], vR[2];
    {
        int gr = T0 * 64 + sr; if (gr > L_ - 1) gr = L_ - 1;
        const __bf16* kp = Kb + kRowBase + (size_t)gr * D_;
        const __bf16* vp = Vtb + vRowBase + T0 * 64;
        kR[0] = *(const u32x4*)&kp[0];  kR[1] = *(const u32x4*)&kp[32];
        vR[0] = *(const u32x4*)&vp[0];  vR[1] = *(const u32x4*)&vp[32];
        *(u32x4*)&Kls[sr][scb]      = kR[0];
        *(u32x4*)&Kls[sr][scb + 32] = kR[1];
        *(u32x4*)&Vls[sr][scb]      = vR[0];
        *(u32x4*)&Vls[sr][scb + 32] = vR[1];
    }

    for (int t = T0; t < T1; ++t) {
        const int kt = t * 64;
        __syncthreads();

        if (t + 1 < T1) {
            int gr = kt + 64 + sr; if (gr > L_ - 1) gr = L_ - 1;
            const __bf16* kp = Kb + kRowBase + (size_t)gr * D_;
            const __bf16* vp = Vtb + vRowBase + (kt + 64);
            kR[0] = *(const u32x4*)&kp[0];  kR[1] = *(const u32x4*)&kp[32];
            vR[0] = *(const u32x4*)&vp[0];  vR[1] = *(const u32x4*)&vp[32];
        }

        const bool fullTile = (kt + 64 <= L_);
#pragma unroll
        for (int st = 0; st < 2; ++st) {
            const int ko = st * 32;

            f32x16 sacc;
#pragma unroll
            for (int r = 0; r < 16; ++r) sacc[r] = 0.f;
            __builtin_amdgcn_s_setprio(1);
#pragma unroll
            for (int c = 0; c < 4; ++c) {
                bf16x8 ak = *(bf16x8*)&Kls[ko + la][c * 16 + hl * 8];
                sacc = __builtin_amdgcn_mfma_f32_32x32x16_bf16(ak, bq[c], sacc, 0, 0, 0);
            }
            __builtin_amdgcn_s_setprio(0);

            float p[16];
            if (fullTile) {
#pragma unroll
                for (int r = 0; r < 16; ++r) p[r] = sacc[r];
            } else {
#pragma unroll
                for (int r = 0; r < 16; ++r) {
                    int kg = kt + ko + (r & 3) + 8 * (r >> 2) + 4 * hl;
                    p[r] = (kg < L_) ? sacc[r] : -1e30f;
                }
            }

            // ---- online softmax, log2 domain; tree max + permlane exchange ----
            float q0m = fmaxf(fmaxf(p[0], p[1]),  fmaxf(p[2], p[3]));
            float q1m = fmaxf(fmaxf(p[4], p[5]),  fmaxf(p[6], p[7]));
            float q2m = fmaxf(fmaxf(p[8], p[9]),  fmaxf(p[10], p[11]));
            float q3m = fmaxf(fmaxf(p[12], p[13]), fmaxf(p[14], p[15]));
            float t0 = fmaxf(fmaxf(q0m, q1m), fmaxf(q2m, q3m));
            u32x2 rm = __builtin_amdgcn_permlane32_swap(b32f(t0), b32f(t0), false, false);
            t0 = fmaxf(f32b(rm[0]), f32b(rm[1]));
            float mn = fmaxf(m, t0);
            const bool noresc = __all(mn == m);   // scl==1 exactly -> skip
            float sclq = noresc ? 1.f : __builtin_amdgcn_exp2f(m - mn);
            m = mn;
#pragma unroll
            for (int r = 0; r < 16; ++r) p[r] = __builtin_amdgcn_exp2f(p[r] - mn);
            float s0 = (p[0] + p[1]) + (p[2] + p[3]);
            float s1 = (p[4] + p[5]) + (p[6] + p[7]);
            float s2 = (p[8] + p[9]) + (p[10] + p[11]);
            float s3 = (p[12] + p[13]) + (p[14] + p[15]);
            float ls = (s0 + s1) + (s2 + s3);
            u32x2 rl = __builtin_amdgcn_permlane32_swap(b32f(ls), b32f(ls), false, false);
            ls = f32b(rl[0]) + f32b(rl[1]);
            lsum = lsum * sclq + ls;
            if (!noresc) {
#pragma unroll
                for (int r = 0; r < 16; ++r) { oT0[r] *= sclq; oT1[r] *= sclq; }
            }

            // ---- P^T -> PV B-frags: permlane32_swap, zero selects ----
            bf16x8 pb[2];
#pragma unroll
            for (int cc = 0; cc < 2; ++cc) {
                uint32_t G0 = pk2f(p[8 * cc + 0], p[8 * cc + 1]);
                uint32_t G1 = pk2f(p[8 * cc + 2], p[8 * cc + 3]);
                uint32_t G2 = pk2f(p[8 * cc + 4], p[8 * cc + 5]);
                uint32_t G3 = pk2f(p[8 * cc + 6], p[8 * cc + 7]);
                u32x2 r02 = __builtin_amdgcn_permlane32_swap(G0, G2, false, false);
                u32x2 r13 = __builtin_amdgcn_permlane32_swap(G1, G3, false, false);
                U4 uh;
                uh.u[0] = r02[0]; uh.u[1] = r13[0];
                uh.u[2] = r02[1]; uh.u[3] = r13[1];
                pb[cc] = uh.f;
            }

            __builtin_amdgcn_s_setprio(1);
#pragma unroll
            for (int cc = 0; cc < 2; ++cc) {
                bf16x8 av0 = *(bf16x8*)&Vls[la][ko + cc * 16 + hl * 8];
                bf16x8 av1 = *(bf16x8*)&Vls[32 + la][ko + cc * 16 + hl * 8];
                oT0 = __builtin_amdgcn_mfma_f32_32x32x16_bf16(av0, pb[cc], oT0, 0, 0, 0);
                oT1 = __builtin_amdgcn_mfma_f32_32x32x16_bf16(av1, pb[cc], oT1, 0, 0, 0);
            }
            __builtin_amdgcn_s_setprio(0);
        }

        __syncthreads();
        if (t + 1 < T1) {
            *(u32x4*)&Kls[sr][scb]      = kR[0];
            *(u32x4*)&Kls[sr][scb + 32] = kR[1];
            *(u32x4*)&Vls[sr][scb]      = vR[0];
            *(u32x4*)&Vls[sr][scb + 32] = vR[1];
        }
    }

    __bf16* Op = Opart + (size_t)s * M_ * D_;
    int qrow = q0 + la;
    if (qrow < L_) {
        __bf16* orow = Op + obase + (size_t)qrow * D_;
#pragma unroll
        for (int bb = 0; bb < 4; ++bb) {
            uint2 uu0, uu1;
            uu0.x = pk2f(oT0[4 * bb + 0], oT0[4 * bb + 1]);
            uu0.y = pk2f(oT0[4 * bb + 2], oT0[4 * bb + 3]);
            uu1.x = pk2f(oT1[4 * bb + 0], oT1[4 * bb + 1]);
            uu1.y = pk2f(oT1[4 * bb + 2], oT1[4 * bb + 3]);
            *(uint2*)&orow[bb * 8 + hl * 4]      = uu0;
            *(uint2*)&orow[32 + bb * 8 + hl * 4] = uu1;
        }
        if (hl == 0) {
            size_t mlidx = (((size_t)s * B_ + b) * H_ + h) * L_ + qrow;
            ml[mlidx * 2]     = m;
            ml[mlidx * 2 + 1] = lsum;
        }
    }
}

// ---------------- merge split-K partials (bf16 in, log2-domain stats) ----------------
__global__ __launch_bounds__(256) void attn_merge_kernel(
    const __bf16* __restrict__ Opart, const float* __restrict__ ml,
    __bf16* __restrict__ Out) {
    int idx = blockIdx.x * 256 + threadIdx.x;
    if (idx >= M_ * 64) return;
    int row = idx >> 6;
    int seg = idx & 63;
    int col0 = seg * 8;
    int h = col0 >> 6;
    int b = row / L_;
    int l = row - b * L_;
    float ms[NSPLIT_], ls[NSPLIT_];
    float mm = -1e30f;
#pragma unroll
    for (int s = 0; s < NSPLIT_; ++s) {
        size_t mi = ((((size_t)s * B_ + b) * H_ + h) * L_ + l) * 2;
        ms[s] = ml[mi];
        ls[s] = ml[mi + 1];
        mm = fmaxf(mm, ms[s]);
    }
    float wsum = 0.f, w[NSPLIT_];
#pragma unroll
    for (int s = 0; s < NSPLIT_; ++s) {
        w[s] = __builtin_amdgcn_exp2f(ms[s] - mm);   // log2-domain stats
        wsum += w[s] * ls[s];
    }
    float inv = 1.f / wsum;
#pragma unroll
    for (int s = 0; s < NSPLIT_; ++s) w[s] *= inv;

    size_t base = (size_t)row * D_ + col0;
    float o[8] = {0.f, 0.f, 0.f, 0.f, 0.f, 0.f, 0.f, 0.f};
#pragma unroll
    for (int s = 0; s < NSPLIT_; ++s) {
        const __bf16* Os = Opart + (size_t)s * M_ * D_;
        u32x4 a = *(const u32x4*)&Os[base];
#pragma unroll
        for (int i = 0; i < 4; ++i) {
            o[2 * i]     += w[s] * bf2f(a[i] & 0xffffu);
            o[2 * i + 1] += w[s] * bf2f(a[i] >> 16);
        }
    }
    U4 u;
#pragma unroll
    for (int i = 0; i < 4; ++i)
        u.u[i] = pk2f(o[2 * i], o[2 * i + 1]);
    *(u32x4*)&Out[base] = *(u32x4*)&u.u[0];
}

// ---------------- fused residual add + LayerNorm (+ optional bf16 out) ----------------
template <bool HIOUT>
__global__ __launch_bounds__(256) void add_ln_kernel(
    const float* __restrict__ X, const float* __restrict__ Y,
    const float* __restrict__ g, const float* __restrict__ be,
    float* __restrict__ Out, __bf16* __restrict__ Oh) {
    int wave = threadIdx.x >> 6;
    int lane = threadIdx.x & 63;
    int row = blockIdx.x * 4 + wave;
    if (row >= M_) return;
    size_t base = (size_t)row * D_;
    int c0 = lane * 4, c1 = 256 + lane * 4;
    float4 xa = *(const float4*)&X[base + c0];
    float4 xb = *(const float4*)&X[base + c1];
    float4 ya = *(const float4*)&Y[base + c0];
    float4 yb = *(const float4*)&Y[base + c1];
    float v[8] = {xa.x + ya.x, xa.y + ya.y, xa.z + ya.z, xa.w + ya.w,
                  xb.x + yb.x, xb.y + yb.y, xb.z + yb.z, xb.w + yb.w};
    float s = 0.f, s2 = 0.f;
#pragma unroll
    for (int i = 0; i < 8; ++i) { s += v[i]; s2 = fmaf(v[i], v[i], s2); }
#pragma unroll
    for (int off = 32; off > 0; off >>= 1) {
        s  += __shfl_xor(s, off);
        s2 += __shfl_xor(s2, off);
    }
    float mean = s * (1.f / D_);
    float var  = s2 * (1.f / D_) - mean * mean;
    float rstd = rsqrtf(var + EPS_);
    float4 ga = *(const float4*)&g[c0];
    float4 gb = *(const float4*)&g[c1];
    float4 ba = *(const float4*)&be[c0];
    float4 bb = *(const float4*)&be[c1];
    float o[8];
    o[0] = (v[0] - mean) * rstd * ga.x + ba.x;
    o[1] = (v[1] - mean) * rstd * ga.y + ba.y;
    o[2] = (v[2] - mean) * rstd * ga.z + ba.z;
    o[3] = (v[3] - mean) * rstd * ga.w + ba.w;
    o[4] = (v[4] - mean) * rstd * gb.x + bb.x;
    o[5] = (v[5] - mean) * rstd * gb.y + bb.y;
    o[6] = (v[6] - mean) * rstd * gb.z + bb.z;
    o[7] = (v[7] - mean) * rstd * gb.w + bb.w;
    *(float4*)&Out[base + c0] = make_float4(o[0], o[1], o[2], o[3]);
    *(float4*)&Out[base + c1] = make_float4(o[4], o[5], o[6], o[7]);
    if (HIOUT) {
        bf16x4 h0, h1;
#pragma unroll
        for (int i = 0; i < 4; ++i) {
            h0[i] = (__bf16)o[i];
            h1[i] = (__bf16)o[4 + i];
        }
        *(bf16x4*)&Oh[base + c0] = h0;
        *(bf16x4*)&Oh[base + c1] = h1;
    }
}

// ---------------- launch ----------------
extern "C" void kernel_launch(void* const* d_in, const int* in_sizes, int n_in,
                              void* d_out, int out_size, void* d_ws, size_t ws_size,
                              hipStream_t stream) {
    const float* embed1 = (const float*)d_in[0];
    const float* embed2 = (const float*)d_in[1];
    const float* cls    = (const float*)d_in[2];
    const float* Wq = (const float*)d_in[3];
    const float* bq = (const float*)d_in[4];
    const float* Wk = (const float*)d_in[5];
    const float* bk = (const float*)d_in[6];
    const float* Wv = (const float*)d_in[7];
    const float* bv = (const float*)d_in[8];
    const float* Wo = (const float*)d_in[9];
    const float* bo = (const float*)d_in[10];
    const float* ln1g = (const float*)d_in[11];
    const float* ln1b = (const float*)d_in[12];
    const float* W1 = (const float*)d_in[13];
    const float* b1 = (const float*)d_in[14];
    const float* W2 = (const float*)d_in[15];
    const float* b2 = (const float*)d_in[16];
    const float* ln2g = (const float*)d_in[17];
    const float* ln2b = (const float*)d_in[18];

    const size_t SZ = (size_t)M_ * D_;        // 4,198,400 floats
    float* ws = (float*)d_ws;
    float* X   = ws;                           // [0,SZ) fp32 residual stream
    __bf16* Xh = (__bf16*)(ws + SZ);           // [SZ,1.5SZ) bf16 of X
    __bf16* X2h = (__bf16*)(ws + SZ + SZ / 2); // [1.5SZ,2SZ) bf16 of X2
    float* Tb  = ws + 2 * SZ;                  // [2SZ,3SZ): fp32 scratch (X2 setup, FFN2 out)
    __bf16* Tbh = (__bf16*)(ws + 2 * SZ + SZ / 2); // merge out (attn phase; Tb fp32 dead then)
    __bf16* Qbh = (__bf16*)(ws + 3 * SZ);      // [3SZ,3.5SZ) bf16 Q (attn phase)
    float* WoOut  = (float*)(ws + 3 * SZ);     // aliases Qbh region (dead after attn)
    __bf16* Kbh = (__bf16*)(ws + 4 * SZ);      // [4SZ,4.5SZ) bf16 K
    __bf16* Vtb = (__bf16*)(ws + 5 * SZ);      // [5SZ,~5.54SZ) bf16 Vt (attn phase)
    __bf16* Hbh = (__bf16*)(ws + 5 * SZ);      // [5SZ,7SZ) bf16 [M,DFF] FFN phase (aliases Vtb)
    float* mlBuf   = ws + 6 * SZ + SZ / 2;     // stats (attn phase)
    __bf16* Opart  = (__bf16*)(ws + 7 * SZ);   // [7SZ,8SZ) 2 bf16 partial O (attn phase)
    __bf16* wreg = (__bf16*)(ws + 9 * SZ);     // bf16 weights

    const size_t NQl = (size_t)D_ * D_;                // 262144 per layer
    const size_t NQ  = (size_t)NLAYER_ * NQl;          // 524288
    const size_t NF  = (size_t)NLAYER_ * DFF_ * D_;    // 2097152
    __bf16* Wqh  = wreg;                 // NQ
    __bf16* Wkvh = Wqh + NQ;             // 2*NQ  [NLAYER][1024][512]
    __bf16* Woh  = Wkvh + 2 * NQ;        // NQ
    __bf16* W1h  = Woh + NQ;             // NF
    __bf16* W2h  = W1h + NF;             // NF

    tobf16_kernel<<<(int)(NQ / 4 + 255) / 256, 256, 0, stream>>>(Wq, Wqh, (int)(NQ / 4));
    tobf16_kernel<<<(int)(NQ / 4 + 255) / 256, 256, 0, stream>>>(Wo, Woh, (int)(NQ / 4));
    tobf16_kernel<<<(int)(NF / 4 + 255) / 256, 256, 0, stream>>>(W1, W1h, (int)(NF / 4));
    tobf16_kernel<<<(int)(NF / 4 + 255) / 256, 256, 0, stream>>>(W2, W2h, (int)(NF / 4));
    for (int l = 0; l < NLAYER_; ++l) {
        tobf16_kernel<<<(int)(NQl / 4 + 255) / 256, 256, 0, stream>>>(
            Wk + l * NQl, Wkvh + l * 2 * NQl, (int)(NQl / 4));
        tobf16_kernel<<<(int)(NQl / 4 + 255) / 256, 256, 0, stream>>>(
            Wv + l * NQl, Wkvh + l * 2 * NQl + NQl, (int)(NQl / 4));
    }

    // build X (fp32, persistent) and X2 (fp32 in Tb scratch, converted once)
    float* X2tmp = Tb;
    write_cls_kernel<<<(B_ * D_) / 256, 256, 0, stream>>>(cls, X, X2tmp);
    transpose_embed_kernel<<<dim3(L0_ / 32, D_ / 32, B_), dim3(32, 8), 0, stream>>>(embed1, X);
    transpose_embed_kernel<<<dim3(L0_ / 32, D_ / 32, B_), dim3(32, 8), 0, stream>>>(embed2, X2tmp);
    tobf16_kernel<<<(int)(SZ / 4 + 255) / 256, 256, 0, stream>>>(X, Xh, (int)(SZ / 4));
    tobf16_kernel<<<(int)(SZ / 4 + 255) / 256, 256, 0, stream>>>(X2tmp, X2h, (int)(SZ / 4));

    const int GM = (M_ + 127) / 128;         // 65
    const int g512  = GM * (512 / 64);       // 520
    const int g1024 = GM * (1024 / 64);      // 1040
    const int g2048 = GM * (2048 / 64);      // 2080
    const int gpad  = (B_ * H_ * DH_ * (LP_ - L_) + 255) / 256;
    const int gmerge = (M_ * 64 + 255) / 256;

    for (int l = 0; l < NLAYER_; ++l) {
        const size_t oQ = (size_t)l * NQl;
        const size_t oF = (size_t)l * DFF_ * D_;

        gemm_mfma_kernel<false, 2><<<g512, 256, 0, stream>>>(
            Xh, Wqh + oQ, bq + l * D_, nullptr, Qbh, M_, D_, D_, QSCALE_);
        gemm_kv_kernel<<<g1024, 256, 0, stream>>>(
            X2h, Wkvh + l * 2 * NQl, bk + l * D_, bv + l * D_, Kbh, Vtb);
        zero_vt_pad_kernel<<<gpad, 256, 0, stream>>>(Vtb);

        attn_mfma_kernel<<<NSPLIT_ * NQT_ * H_ * B_, 256, 0, stream>>>(
            Qbh, Kbh, Vtb, Opart, mlBuf);
        attn_merge_kernel<<<gmerge, 256, 0, stream>>>(Opart, mlBuf, Tbh);

        gemm_mfma_kernel<false, 0><<<g512, 256, 0, stream>>>(
            Tbh, Woh + oQ, bo + l * D_, WoOut, nullptr, M_, D_, D_, 1.f);

        add_ln_kernel<true><<<(M_ + 3) / 4, 256, 0, stream>>>(
            X, WoOut, ln1g + l * D_, ln1b + l * D_, X, Xh);

        gemm_mfma_kernel<true, 2><<<g2048, 256, 0, stream>>>(
            Xh, W1h + oF, b1 + l * DFF_, nullptr, Hbh, M_, DFF_, D_, 1.f);
        gemm_mfma_kernel<false, 0><<<g512, 256, 0, stream>>>(
            Hbh, W2h + oF, b2 + l * D_, Tb, nullptr, M_, D_, DFF_, 1.f);

        if (l == NLAYER_ - 1) {
            add_ln_kernel<false><<<(M_ + 3) / 4, 256, 0, stream>>>(
                X, Tb, ln2g + l * D_, ln2b + l * D_, (float*)d_out, nullptr);
        } else {
            add_ln_kernel<true><<<(M_ + 3) / 4, 256, 0, stream>>>(
                X, Tb, ln2g + l * D_, ln2b + l * D_, X, Xh);
        }
    }
}

// Round 29
// 458.425 us; speedup vs baseline: 1.1683x; 1.1683x over previous
//
#include <hip/hip_runtime.h>
#include <hip/hip_bf16.h>

// ---------------- problem constants ----------------
constexpr int B_   = 8;
constexpr int D_   = 512;
constexpr int L0_  = 1024;
constexpr int L_   = 1025;          // L0 + cls
constexpr int H_   = 8;
constexpr int DH_  = 64;
constexpr int DFF_ = 2048;
constexpr int NLAYER_ = 2;
constexpr int M_   = B_ * L_;       // 8200 rows
constexpr int LP_  = 1088;          // padded L for Vt (17*64)
constexpr int NQT_ = 9;             // ceil(L/128) attn q-tiles
constexpr int NSPLIT_ = 2;          // K-range partitions (flash-decoding)
constexpr float EPS_   = 1e-6f;
// 0.125 * log2(e): scores produced directly in log2 domain (exp2 softmax)
constexpr float QSCALE_ = 0.18033688011112042f;

#define DEV_INLINE __device__ __forceinline__

typedef __attribute__((ext_vector_type(8)))  __bf16 bf16x8;
typedef __attribute__((ext_vector_type(4)))  __bf16 bf16x4;
typedef __attribute__((ext_vector_type(4)))  float  f32x4;
typedef __attribute__((ext_vector_type(16))) float  f32x16;
typedef __attribute__((ext_vector_type(4)))  unsigned int u32x4;
typedef __attribute__((ext_vector_type(2)))  unsigned int u32x2;

union U4 { uint32_t u[4]; bf16x8 f; };

DEV_INLINE float gelu_exact(float x) {
    return 0.5f * x * (1.f + erff(x * 0.70710678118654752f));
}

DEV_INLINE uint16_t bfbits(float v) {
    __bf16 h = (__bf16)v;
    return __builtin_bit_cast(uint16_t, h);
}
DEV_INLINE uint32_t pk2f(float a, float b) {
    return (uint32_t)bfbits(a) | ((uint32_t)bfbits(b) << 16);
}
DEV_INLINE float bf2f(uint32_t bits16) {           // low 16 bits = bf16
    uint32_t u = bits16 << 16;
    return __builtin_bit_cast(float, u);
}
DEV_INLINE uint32_t b32f(float f) { return __builtin_bit_cast(uint32_t, f); }
DEV_INLINE float f32b(uint32_t u) { return __builtin_bit_cast(float, u); }

// async global->LDS DMA, 16B per lane; LDS dest = wave-uniform base + lane*16
DEV_INLINE void gload16(const __bf16* g, __bf16* l) {
    __builtin_amdgcn_global_load_lds(
        (const __attribute__((address_space(1))) void*)g,
        (__attribute__((address_space(3))) void*)l,
        16, 0, 0);
}

// ---------------- fp32 -> bf16 ----------------
__global__ __launch_bounds__(256) void tobf16_kernel(
    const float* __restrict__ src, __bf16* __restrict__ dst, int n4) {
    int i = blockIdx.x * 256 + threadIdx.x;
    if (i >= n4) return;
    float4 v = *(const float4*)&src[i * 4];
    bf16x4 h;
    h[0] = (__bf16)v.x; h[1] = (__bf16)v.y;
    h[2] = (__bf16)v.z; h[3] = (__bf16)v.w;
    *(bf16x4*)&dst[i * 4] = h;
}

// ---------------- zero Vt pad tokens (l = L_..LP_-1), bf16 ----------------
// CRITICAL: pad tokens feed PV MFMA with P=0; garbage bits can alias bf16
// Inf/NaN and 0*Inf = NaN (R10 failure). Must be zeroed every layer.
__global__ __launch_bounds__(256) void zero_vt_pad_kernel(__bf16* __restrict__ Vt) {
    constexpr int PAD = LP_ - L_;                 // 63
    int idx = blockIdx.x * 256 + threadIdx.x;
    int total = B_ * H_ * DH_ * PAD;
    if (idx >= total) return;
    int row = idx / PAD;
    int c   = idx - row * PAD;
    Vt[(size_t)row * LP_ + L_ + c] = (__bf16)0.f;
}

// ---------------- build x1/x2 ----------------
__global__ __launch_bounds__(256) void write_cls_kernel(
    const float* __restrict__ cls, float* __restrict__ X1, float* __restrict__ X2) {
    int idx = blockIdx.x * 256 + threadIdx.x;
    int b = idx >> 9;
    int d = idx & 511;
    float v = cls[d];
    X1[(size_t)b * L_ * D_ + d] = v;
    X2[(size_t)b * L_ * D_ + d] = v;
}

// embed [B, D, L0] -> X rows 1..L0
__global__ __launch_bounds__(256) void transpose_embed_kernel(
    const float* __restrict__ e, float* __restrict__ X) {
    __shared__ float tile[32][33];
    int b  = blockIdx.z;
    int i0 = blockIdx.x * 32;
    int d0 = blockIdx.y * 32;
    int tx = threadIdx.x;
    int ty = threadIdx.y;
#pragma unroll
    for (int j = 0; j < 32; j += 8)
        tile[ty + j][tx] = e[((size_t)b * D_ + d0 + ty + j) * L0_ + i0 + tx];
    __syncthreads();
#pragma unroll
    for (int j = 0; j < 32; j += 8)
        X[((size_t)b * L_ + 1 + i0 + ty + j) * D_ + d0 + tx] = tile[tx][ty + j];
}

// ---------------- pure bf16 MFMA GEMM, BK=64, global_load_lds staging ----------------
// Single-buffer (R27 structure -- 6 blocks/CU). A-panel-major block mapping:
// consecutive bids share the 128-row A-panel (L2-resident); W streams and
// stays L2-resident (<=2 MB). OUTMODE: 0 = fp32, 2 = bf16.
template <bool GELU, int OUTMODE>
__global__ __launch_bounds__(256) void gemm_mfma_kernel(
    const __bf16* __restrict__ A, const __bf16* __restrict__ Wh,
    const float* __restrict__ bias, float* __restrict__ C,
    __bf16* __restrict__ Ch, int M, int N, int K, float oscale) {
    constexpr int BM = 128, BN = 64, BK = 64;
    __shared__ alignas(16) __bf16 Ahs[BM * BK];   // [128][64] linear
    __shared__ alignas(16) __bf16 Bhs[BN * BK];   // [64][64] linear

    const int GN = N / BN;
    const int nwg = gridDim.x;
    int bid = blockIdx.x;
    {
        int q = nwg >> 3, r = nwg & 7;
        int xcd = bid & 7, pos = bid >> 3;
        bid = (xcd < r) ? xcd * (q + 1) + pos
                        : r * (q + 1) + (xcd - r) * q + pos;
    }
    const int bm = bid / GN;           // consecutive bids: same A-panel
    const int bn = bid % GN;
    const int m0 = bm * BM;
    const int n0 = bn * BN;

    const int tid  = threadIdx.x;
    const int lane = tid & 63;
    const int wv   = tid >> 6;
    const int wr   = wv >> 1;
    const int wc   = wv & 1;
    const int fr   = lane & 15;
    const int fq   = lane >> 4;
    const int fq8  = fq * 8;
    const int mb   = wr * 64;
    const int nb   = wc * 32;
    const int swz  = (fr & 7) << 3;               // read-side col XOR (elements)

    // staging source offsets (pre-swizzled col within 64-elem slice)
    const int srcColE = (((lane & 7) ^ (lane >> 3)) << 3);
    size_t aSrc[4];
#pragma unroll
    for (int j = 0; j < 4; ++j) {
        int row = (wv * 4 + j) * 8 + (lane >> 3);
        int ar = m0 + row; if (ar > M - 1) ar = M - 1;
        aSrc[j] = (size_t)ar * K + srcColE;
    }
    size_t bSrc[2];
#pragma unroll
    for (int j = 0; j < 2; ++j) {
        int row = (wv * 2 + j) * 8 + (lane >> 3);
        bSrc[j] = (size_t)(n0 + row) * K + srcColE;
    }

    f32x4 acc[4][2];
#pragma unroll
    for (int i = 0; i < 4; ++i)
#pragma unroll
        for (int j = 0; j < 2; ++j) acc[i][j] = (f32x4){0.f, 0.f, 0.f, 0.f};

    const int nk = K / BK;
    // prologue: stage tile 0
#pragma unroll
    for (int j = 0; j < 4; ++j) gload16(A + aSrc[j], &Ahs[(wv * 4 + j) * 512]);
#pragma unroll
    for (int j = 0; j < 2; ++j) gload16(Wh + bSrc[j], &Bhs[(wv * 2 + j) * 512]);

    for (int kt = 0; kt < nk; ++kt) {
        __syncthreads();   // vmcnt(0) drain: DMA landed

#pragma unroll
        for (int ks = 0; ks < 2; ++ks) {
            bf16x8 ah[4], bh[2];
#pragma unroll
            for (int i = 0; i < 4; ++i)
                ah[i] = *(bf16x8*)&Ahs[(mb + i * 16 + fr) * 64 + ((ks * 32 + fq8) ^ swz)];
#pragma unroll
            for (int j = 0; j < 2; ++j)
                bh[j] = *(bf16x8*)&Bhs[(nb + j * 16 + fr) * 64 + ((ks * 32 + fq8) ^ swz)];
#pragma unroll
            for (int i = 0; i < 4; ++i)
#pragma unroll
                for (int j = 0; j < 2; ++j)
                    acc[i][j] = __builtin_amdgcn_mfma_f32_16x16x32_bf16(ah[i], bh[j], acc[i][j], 0, 0, 0);
        }
        __syncthreads();   // all waves done reading

        if (kt + 1 < nk) {
            int k0 = (kt + 1) * BK;
#pragma unroll
            for (int j = 0; j < 4; ++j) gload16(A + aSrc[j] + k0, &Ahs[(wv * 4 + j) * 512]);
#pragma unroll
            for (int j = 0; j < 2; ++j) gload16(Wh + bSrc[j] + k0, &Bhs[(wv * 2 + j) * 512]);
        }
    }

    const int ccol0 = n0 + nb + fr;
    const float b0 = bias[ccol0];
    const float b1 = bias[ccol0 + 16];
#pragma unroll
    for (int i = 0; i < 4; ++i) {
#pragma unroll
        for (int r = 0; r < 4; ++r) {
            int row = m0 + mb + i * 16 + fq * 4 + r;
            if (row < M) {
                float v0 = acc[i][0][r] + b0;
                float v1 = acc[i][1][r] + b1;
                if (GELU) { v0 = gelu_exact(v0); v1 = gelu_exact(v1); }
                v0 *= oscale;
                v1 *= oscale;
                if (OUTMODE == 2) {
                    Ch[(size_t)row * N + ccol0]      = (__bf16)v0;
                    Ch[(size_t)row * N + ccol0 + 16] = (__bf16)v1;
                } else {
                    C[(size_t)row * N + ccol0]      = v0;
                    C[(size_t)row * N + ccol0 + 16] = v1;
                }
            }
        }
    }
}

// ---------------- fused K+V GEMM, gload_lds staging (V stored transposed) ----------------
__global__ __launch_bounds__(256) void gemm_kv_kernel(
    const __bf16* __restrict__ A, const __bf16* __restrict__ Wh,
    const float* __restrict__ biasK, const float* __restrict__ biasV,
    __bf16* __restrict__ Kb, __bf16* __restrict__ Vt) {
    constexpr int BM = 128, BN = 64, BK = 64, K = 512, N = 1024;
    __shared__ alignas(16) __bf16 Ahs[BM * BK];
    __shared__ alignas(16) __bf16 Bhs[BN * BK];

    constexpr int GN = N / BN;     // 16
    const int nwg = gridDim.x;
    int bid = blockIdx.x;
    {
        int q = nwg >> 3, r = nwg & 7;
        int xcd = bid & 7, pos = bid >> 3;
        bid = (xcd < r) ? xcd * (q + 1) + pos
                        : r * (q + 1) + (xcd - r) * q + pos;
    }
    const int bm = bid / GN;
    const int bn = bid % GN;
    const int m0 = bm * BM;
    const int n0 = bn * BN;

    const int tid  = threadIdx.x;
    const int lane = tid & 63;
    const int wv   = tid >> 6;
    const int wr   = wv >> 1;
    const int wc   = wv & 1;
    const int fr   = lane & 15;
    const int fq   = lane >> 4;
    const int fq8  = fq * 8;
    const int mb   = wr * 64;
    const int nb   = wc * 32;
    const int swz  = (fr & 7) << 3;

    const int srcColE = (((lane & 7) ^ (lane >> 3)) << 3);
    size_t aSrc[4];
#pragma unroll
    for (int j = 0; j < 4; ++j) {
        int row = (wv * 4 + j) * 8 + (lane >> 3);
        int ar = m0 + row; if (ar > M_ - 1) ar = M_ - 1;
        aSrc[j] = (size_t)ar * K + srcColE;
    }
    size_t bSrc[2];
#pragma unroll
    for (int j = 0; j < 2; ++j) {
        int row = (wv * 2 + j) * 8 + (lane >> 3);
        bSrc[j] = (size_t)(n0 + row) * K + srcColE;
    }

    f32x4 acc[4][2];
#pragma unroll
    for (int i = 0; i < 4; ++i)
#pragma unroll
        for (int j = 0; j < 2; ++j) acc[i][j] = (f32x4){0.f, 0.f, 0.f, 0.f};

    const int nk = K / BK;
#pragma unroll
    for (int j = 0; j < 4; ++j) gload16(A + aSrc[j], &Ahs[(wv * 4 + j) * 512]);
#pragma unroll
    for (int j = 0; j < 2; ++j) gload16(Wh + bSrc[j], &Bhs[(wv * 2 + j) * 512]);

    for (int kt = 0; kt < nk; ++kt) {
        __syncthreads();

#pragma unroll
        for (int ks = 0; ks < 2; ++ks) {
            bf16x8 ah[4], bh[2];
#pragma unroll
            for (int i = 0; i < 4; ++i)
                ah[i] = *(bf16x8*)&Ahs[(mb + i * 16 + fr) * 64 + ((ks * 32 + fq8) ^ swz)];
#pragma unroll
            for (int j = 0; j < 2; ++j)
                bh[j] = *(bf16x8*)&Bhs[(nb + j * 16 + fr) * 64 + ((ks * 32 + fq8) ^ swz)];
#pragma unroll
            for (int i = 0; i < 4; ++i)
#pragma unroll
                for (int j = 0; j < 2; ++j)
                    acc[i][j] = __builtin_amdgcn_mfma_f32_16x16x32_bf16(ah[i], bh[j], acc[i][j], 0, 0, 0);
        }
        __syncthreads();

        if (kt + 1 < nk) {
            int k0 = (kt + 1) * BK;
#pragma unroll
            for (int j = 0; j < 4; ++j) gload16(A + aSrc[j] + k0, &Ahs[(wv * 4 + j) * 512]);
#pragma unroll
            for (int j = 0; j < 2; ++j) gload16(Wh + bSrc[j] + k0, &Bhs[(wv * 2 + j) * 512]);
        }
    }

    const int ccol0 = n0 + nb + fr;
    if (n0 < 512) {
        const float b0 = biasK[ccol0];
        const float b1 = biasK[ccol0 + 16];
#pragma unroll
        for (int i = 0; i < 4; ++i) {
#pragma unroll
            for (int r = 0; r < 4; ++r) {
                int row = m0 + mb + i * 16 + fq * 4 + r;
                if (row < M_) {
                    Kb[(size_t)row * 512 + ccol0]      = (__bf16)(acc[i][0][r] + b0);
                    Kb[(size_t)row * 512 + ccol0 + 16] = (__bf16)(acc[i][1][r] + b1);
                }
            }
        }
    } else {
        const int cv = ccol0 - 512;
        const int h2 = cv >> 6, d2 = cv & 63;
        const float b0 = biasV[cv];
        const float b1 = biasV[cv + 16];
#pragma unroll
        for (int i = 0; i < 4; ++i) {
#pragma unroll
            for (int r = 0; r < 4; ++r) {
                int row = m0 + mb + i * 16 + fq * 4 + r;
                if (row < M_) {
                    int b2 = row / L_;
                    int l2 = row - b2 * L_;
                    size_t vb = (size_t)(b2 * H_ + h2) * DH_ * LP_;
                    Vt[vb + (size_t)d2 * LP_ + l2]        = (__bf16)(acc[i][0][r] + b0);
                    Vt[vb + (size_t)(d2 + 16) * LP_ + l2] = (__bf16)(acc[i][1][r] + b1);
                }
            }
        }
    }
}

// ---------------- MFMA flash attention: 32x32 swapped form, exp2 softmax ----------------
// Scores arrive in log2 domain (QSCALE_ folded into Q). All lane^32 exchanges
// via permlane32_swap (VALU pipe, zero selects). Tree reductions; setprio on MFMA.
__global__ __launch_bounds__(256) void attn_mfma_kernel(
    const __bf16* __restrict__ Qb, const __bf16* __restrict__ Kb,
    const __bf16* __restrict__ Vtb, __bf16* __restrict__ Opart,
    float* __restrict__ ml) {
    constexpr int LDP = 72;                   // bf16 row stride (144B)
    constexpr int NT = (L_ + 63) / 64;        // 17
    __shared__ alignas(16) __bf16 Kls[64][LDP];
    __shared__ alignas(16) __bf16 Vls[64][LDP];

    const int tid  = threadIdx.x;
    const int lane = tid & 63;
    const int wv   = tid >> 6;
    const int la   = lane & 31;               // q column (and k/d row for frags)
    const int hl   = lane >> 5;               // lane half

    int bid = blockIdx.x;
    int swz = (bid & 7) * (NSPLIT_ * NQT_ * H_ * B_ / 8) + (bid >> 3);
    const int s   = swz / (NQT_ * H_ * B_);
    int rem = swz - s * (NQT_ * H_ * B_);
    const int qt = rem % NQT_;
    const int bh = rem / NQT_;
    const int h = bh & 7, b = bh >> 3;
    const int q0 = qt * 128 + wv * 32;
    const int T0 = (NT * s) / NSPLIT_;
    const int T1 = (NT * (s + 1)) / NSPLIT_;
    const size_t obase = (size_t)b * L_ * D_ + h * DH_;

    bf16x8 bq[4];
    {
        int gq = q0 + la; if (gq > L_ - 1) gq = L_ - 1;
        const __bf16* qrow = Qb + (size_t)(b * L_ + gq) * D_ + h * DH_;
#pragma unroll
        for (int c = 0; c < 4; ++c)
            bq[c] = *(const bf16x8*)&qrow[c * 16 + hl * 8];
    }

    float m = -1e30f, lsum = 0.f;
    f32x16 oT0, oT1;
#pragma unroll
    for (int r = 0; r < 16; ++r) { oT0[r] = 0.f; oT1[r] = 0.f; }

    const int sr  = tid >> 2;
    const int scb = (tid & 3) * 8;
    const size_t kRowBase = (size_t)(b * L_) * D_ + h * DH_ + scb;
    const size_t vRowBase = ((size_t)bh * DH_ + sr) * LP_ + scb;

    u32x4 kR[2], vR[2];
    {
        int gr = T0 * 64 + sr; if (gr > L_ - 1) gr = L_ - 1;
        const __bf16* kp = Kb + kRowBase + (size_t)gr * D_;
        const __bf16* vp = Vtb + vRowBase + T0 * 64;
        kR[0] = *(const u32x4*)&kp[0];  kR[1] = *(const u32x4*)&kp[32];
        vR[0] = *(const u32x4*)&vp[0];  vR[1] = *(const u32x4*)&vp[32];
        *(u32x4*)&Kls[sr][scb]      = kR[0];
        *(u32x4*)&Kls[sr][scb + 32] = kR[1];
        *(u32x4*)&Vls[sr][scb]      = vR[0];
        *(u32x4*)&Vls[sr][scb + 32] = vR[1];
    }

    for (int t = T0; t < T1; ++t) {
        const int kt = t * 64;
        __syncthreads();

        if (t + 1 < T1) {
            int gr = kt + 64 + sr; if (gr > L_ - 1) gr = L_ - 1;
            const __bf16* kp = Kb + kRowBase + (size_t)gr * D_;
            const __bf16* vp = Vtb + vRowBase + (kt + 64);
            kR[0] = *(const u32x4*)&kp[0];  kR[1] = *(const u32x4*)&kp[32];
            vR[0] = *(const u32x4*)&vp[0];  vR[1] = *(const u32x4*)&vp[32];
        }

        const bool fullTile = (kt + 64 <= L_);
#pragma unroll
        for (int st = 0; st < 2; ++st) {
            const int ko = st * 32;

            f32x16 sacc;
#pragma unroll
            for (int r = 0; r < 16; ++r) sacc[r] = 0.f;
            __builtin_amdgcn_s_setprio(1);
#pragma unroll
            for (int c = 0; c < 4; ++c) {
                bf16x8 ak = *(bf16x8*)&Kls[ko + la][c * 16 + hl * 8];
                sacc = __builtin_amdgcn_mfma_f32_32x32x16_bf16(ak, bq[c], sacc, 0, 0, 0);
            }
            __builtin_amdgcn_s_setprio(0);

            float p[16];
            if (fullTile) {
#pragma unroll
                for (int r = 0; r < 16; ++r) p[r] = sacc[r];
            } else {
#pragma unroll
                for (int r = 0; r < 16; ++r) {
                    int kg = kt + ko + (r & 3) + 8 * (r >> 2) + 4 * hl;
                    p[r] = (kg < L_) ? sacc[r] : -1e30f;
                }
            }

            // ---- online softmax, log2 domain; tree max + permlane exchange ----
            float q0m = fmaxf(fmaxf(p[0], p[1]),  fmaxf(p[2], p[3]));
            float q1m = fmaxf(fmaxf(p[4], p[5]),  fmaxf(p[6], p[7]));
            float q2m = fmaxf(fmaxf(p[8], p[9]),  fmaxf(p[10], p[11]));
            float q3m = fmaxf(fmaxf(p[12], p[13]), fmaxf(p[14], p[15]));
            float t0 = fmaxf(fmaxf(q0m, q1m), fmaxf(q2m, q3m));
            u32x2 rm = __builtin_amdgcn_permlane32_swap(b32f(t0), b32f(t0), false, false);
            t0 = fmaxf(f32b(rm[0]), f32b(rm[1]));
            float mn = fmaxf(m, t0);
            const bool noresc = __all(mn == m);   // scl==1 exactly -> skip
            float sclq = noresc ? 1.f : __builtin_amdgcn_exp2f(m - mn);
            m = mn;
#pragma unroll
            for (int r = 0; r < 16; ++r) p[r] = __builtin_amdgcn_exp2f(p[r] - mn);
            float s0 = (p[0] + p[1]) + (p[2] + p[3]);
            float s1 = (p[4] + p[5]) + (p[6] + p[7]);
            float s2 = (p[8] + p[9]) + (p[10] + p[11]);
            float s3 = (p[12] + p[13]) + (p[14] + p[15]);
            float ls = (s0 + s1) + (s2 + s3);
            u32x2 rl = __builtin_amdgcn_permlane32_swap(b32f(ls), b32f(ls), false, false);
            ls = f32b(rl[0]) + f32b(rl[1]);
            lsum = lsum * sclq + ls;
            if (!noresc) {
#pragma unroll
                for (int r = 0; r < 16; ++r) { oT0[r] *= sclq; oT1[r] *= sclq; }
            }

            // ---- P^T -> PV B-frags: permlane32_swap, zero selects ----
            bf16x8 pb[2];
#pragma unroll
            for (int cc = 0; cc < 2; ++cc) {
                uint32_t G0 = pk2f(p[8 * cc + 0], p[8 * cc + 1]);
                uint32_t G1 = pk2f(p[8 * cc + 2], p[8 * cc + 3]);
                uint32_t G2 = pk2f(p[8 * cc + 4], p[8 * cc + 5]);
                uint32_t G3 = pk2f(p[8 * cc + 6], p[8 * cc + 7]);
                u32x2 r02 = __builtin_amdgcn_permlane32_swap(G0, G2, false, false);
                u32x2 r13 = __builtin_amdgcn_permlane32_swap(G1, G3, false, false);
                U4 uh;
                uh.u[0] = r02[0]; uh.u[1] = r13[0];
                uh.u[2] = r02[1]; uh.u[3] = r13[1];
                pb[cc] = uh.f;
            }

            __builtin_amdgcn_s_setprio(1);
#pragma unroll
            for (int cc = 0; cc < 2; ++cc) {
                bf16x8 av0 = *(bf16x8*)&Vls[la][ko + cc * 16 + hl * 8];
                bf16x8 av1 = *(bf16x8*)&Vls[32 + la][ko + cc * 16 + hl * 8];
                oT0 = __builtin_amdgcn_mfma_f32_32x32x16_bf16(av0, pb[cc], oT0, 0, 0, 0);
                oT1 = __builtin_amdgcn_mfma_f32_32x32x16_bf16(av1, pb[cc], oT1, 0, 0, 0);
            }
            __builtin_amdgcn_s_setprio(0);
        }

        __syncthreads();
        if (t + 1 < T1) {
            *(u32x4*)&Kls[sr][scb]      = kR[0];
            *(u32x4*)&Kls[sr][scb + 32] = kR[1];
            *(u32x4*)&Vls[sr][scb]      = vR[0];
            *(u32x4*)&Vls[sr][scb + 32] = vR[1];
        }
    }

    __bf16* Op = Opart + (size_t)s * M_ * D_;
    int qrow = q0 + la;
    if (qrow < L_) {
        __bf16* orow = Op + obase + (size_t)qrow * D_;
#pragma unroll
        for (int bb = 0; bb < 4; ++bb) {
            uint2 uu0, uu1;
            uu0.x = pk2f(oT0[4 * bb + 0], oT0[4 * bb + 1]);
            uu0.y = pk2f(oT0[4 * bb + 2], oT0[4 * bb + 3]);
            uu1.x = pk2f(oT1[4 * bb + 0], oT1[4 * bb + 1]);
            uu1.y = pk2f(oT1[4 * bb + 2], oT1[4 * bb + 3]);
            *(uint2*)&orow[bb * 8 + hl * 4]      = uu0;
            *(uint2*)&orow[32 + bb * 8 + hl * 4] = uu1;
        }
        if (hl == 0) {
            size_t mlidx = (((size_t)s * B_ + b) * H_ + h) * L_ + qrow;
            ml[mlidx * 2]     = m;
            ml[mlidx * 2 + 1] = lsum;
        }
    }
}

// ---------------- merge split-K partials (bf16 in, log2-domain stats) ----------------
__global__ __launch_bounds__(256) void attn_merge_kernel(
    const __bf16* __restrict__ Opart, const float* __restrict__ ml,
    __bf16* __restrict__ Out) {
    int idx = blockIdx.x * 256 + threadIdx.x;
    if (idx >= M_ * 64) return;
    int row = idx >> 6;
    int seg = idx & 63;
    int col0 = seg * 8;
    int h = col0 >> 6;
    int b = row / L_;
    int l = row - b * L_;
    float ms[NSPLIT_], ls[NSPLIT_];
    float mm = -1e30f;
#pragma unroll
    for (int s = 0; s < NSPLIT_; ++s) {
        size_t mi = ((((size_t)s * B_ + b) * H_ + h) * L_ + l) * 2;
        ms[s] = ml[mi];
        ls[s] = ml[mi + 1];
        mm = fmaxf(mm, ms[s]);
    }
    float wsum = 0.f, w[NSPLIT_];
#pragma unroll
    for (int s = 0; s < NSPLIT_; ++s) {
        w[s] = __builtin_amdgcn_exp2f(ms[s] - mm);   // log2-domain stats
        wsum += w[s] * ls[s];
    }
    float inv = 1.f / wsum;
#pragma unroll
    for (int s = 0; s < NSPLIT_; ++s) w[s] *= inv;

    size_t base = (size_t)row * D_ + col0;
    float o[8] = {0.f, 0.f, 0.f, 0.f, 0.f, 0.f, 0.f, 0.f};
#pragma unroll
    for (int s = 0; s < NSPLIT_; ++s) {
        const __bf16* Os = Opart + (size_t)s * M_ * D_;
        u32x4 a = *(const u32x4*)&Os[base];
#pragma unroll
        for (int i = 0; i < 4; ++i) {
            o[2 * i]     += w[s] * bf2f(a[i] & 0xffffu);
            o[2 * i + 1] += w[s] * bf2f(a[i] >> 16);
        }
    }
    U4 u;
#pragma unroll
    for (int i = 0; i < 4; ++i)
        u.u[i] = pk2f(o[2 * i], o[2 * i + 1]);
    *(u32x4*)&Out[base] = *(u32x4*)&u.u[0];
}

// ---------------- fused residual add + LayerNorm (+ optional bf16 out) ----------------
template <bool HIOUT>
__global__ __launch_bounds__(256) void add_ln_kernel(
    const float* __restrict__ X, const float* __restrict__ Y,
    const float* __restrict__ g, const float* __restrict__ be,
    float* __restrict__ Out, __bf16* __restrict__ Oh) {
    int wave = threadIdx.x >> 6;
    int lane = threadIdx.x & 63;
    int row = blockIdx.x * 4 + wave;
    if (row >= M_) return;
    size_t base = (size_t)row * D_;
    int c0 = lane * 4, c1 = 256 + lane * 4;
    float4 xa = *(const float4*)&X[base + c0];
    float4 xb = *(const float4*)&X[base + c1];
    float4 ya = *(const float4*)&Y[base + c0];
    float4 yb = *(const float4*)&Y[base + c1];
    float v[8] = {xa.x + ya.x, xa.y + ya.y, xa.z + ya.z, xa.w + ya.w,
                  xb.x + yb.x, xb.y + yb.y, xb.z + yb.z, xb.w + yb.w};
    float s = 0.f, s2 = 0.f;
#pragma unroll
    for (int i = 0; i < 8; ++i) { s += v[i]; s2 = fmaf(v[i], v[i], s2); }
#pragma unroll
    for (int off = 32; off > 0; off >>= 1) {
        s  += __shfl_xor(s, off);
        s2 += __shfl_xor(s2, off);
    }
    float mean = s * (1.f / D_);
    float var  = s2 * (1.f / D_) - mean * mean;
    float rstd = rsqrtf(var + EPS_);
    float4 ga = *(const float4*)&g[c0];
    float4 gb = *(const float4*)&g[c1];
    float4 ba = *(const float4*)&be[c0];
    float4 bb = *(const float4*)&be[c1];
    float o[8];
    o[0] = (v[0] - mean) * rstd * ga.x + ba.x;
    o[1] = (v[1] - mean) * rstd * ga.y + ba.y;
    o[2] = (v[2] - mean) * rstd * ga.z + ba.z;
    o[3] = (v[3] - mean) * rstd * ga.w + ba.w;
    o[4] = (v[4] - mean) * rstd * gb.x + bb.x;
    o[5] = (v[5] - mean) * rstd * gb.y + bb.y;
    o[6] = (v[6] - mean) * rstd * gb.z + bb.z;
    o[7] = (v[7] - mean) * rstd * gb.w + bb.w;
    *(float4*)&Out[base + c0] = make_float4(o[0], o[1], o[2], o[3]);
    *(float4*)&Out[base + c1] = make_float4(o[4], o[5], o[6], o[7]);
    if (HIOUT) {
        bf16x4 h0, h1;
#pragma unroll
        for (int i = 0; i < 4; ++i) {
            h0[i] = (__bf16)o[i];
            h1[i] = (__bf16)o[4 + i];
        }
        *(bf16x4*)&Oh[base + c0] = h0;
        *(bf16x4*)&Oh[base + c1] = h1;
    }
}

// ---------------- launch ----------------
extern "C" void kernel_launch(void* const* d_in, const int* in_sizes, int n_in,
                              void* d_out, int out_size, void* d_ws, size_t ws_size,
                              hipStream_t stream) {
    const float* embed1 = (const float*)d_in[0];
    const float* embed2 = (const float*)d_in[1];
    const float* cls    = (const float*)d_in[2];
    const float* Wq = (const float*)d_in[3];
    const float* bq = (const float*)d_in[4];
    const float* Wk = (const float*)d_in[5];
    const float* bk = (const float*)d_in[6];
    const float* Wv = (const float*)d_in[7];
    const float* bv = (const float*)d_in[8];
    const float* Wo = (const float*)d_in[9];
    const float* bo = (const float*)d_in[10];
    const float* ln1g = (const float*)d_in[11];
    const float* ln1b = (const float*)d_in[12];
    const float* W1 = (const float*)d_in[13];
    const float* b1 = (const float*)d_in[14];
    const float* W2 = (const float*)d_in[15];
    const float* b2 = (const float*)d_in[16];
    const float* ln2g = (const float*)d_in[17];
    const float* ln2b = (const float*)d_in[18];

    const size_t SZ = (size_t)M_ * D_;        // 4,198,400 floats
    float* ws = (float*)d_ws;
    float* X   = ws;                           // [0,SZ) fp32 residual stream
    __bf16* Xh = (__bf16*)(ws + SZ);           // [SZ,1.5SZ) bf16 of X
    __bf16* X2h = (__bf16*)(ws + SZ + SZ / 2); // [1.5SZ,2SZ) bf16 of X2
    float* Tb  = ws + 2 * SZ;                  // [2SZ,3SZ): fp32 scratch (X2 setup, FFN2 out)
    __bf16* Tbh = (__bf16*)(ws + 2 * SZ + SZ / 2); // merge out (attn phase; Tb fp32 dead then)
    __bf16* Qbh = (__bf16*)(ws + 3 * SZ);      // [3SZ,3.5SZ) bf16 Q (attn phase)
    float* WoOut  = (float*)(ws + 3 * SZ);     // aliases Qbh region (dead after attn)
    __bf16* Kbh = (__bf16*)(ws + 4 * SZ);      // [4SZ,4.5SZ) bf16 K
    __bf16* Vtb = (__bf16*)(ws + 5 * SZ);      // [5SZ,~5.54SZ) bf16 Vt (attn phase)
    __bf16* Hbh = (__bf16*)(ws + 5 * SZ);      // [5SZ,7SZ) bf16 [M,DFF] FFN phase (aliases Vtb)
    float* mlBuf   = ws + 6 * SZ + SZ / 2;     // stats (attn phase)
    __bf16* Opart  = (__bf16*)(ws + 7 * SZ);   // [7SZ,8SZ) 2 bf16 partial O (attn phase)
    __bf16* wreg = (__bf16*)(ws + 9 * SZ);     // bf16 weights

    const size_t NQl = (size_t)D_ * D_;                // 262144 per layer
    const size_t NQ  = (size_t)NLAYER_ * NQl;          // 524288
    const size_t NF  = (size_t)NLAYER_ * DFF_ * D_;    // 2097152
    __bf16* Wqh  = wreg;                 // NQ
    __bf16* Wkvh = Wqh + NQ;             // 2*NQ  [NLAYER][1024][512]
    __bf16* Woh  = Wkvh + 2 * NQ;        // NQ
    __bf16* W1h  = Woh + NQ;             // NF
    __bf16* W2h  = W1h + NF;             // NF

    tobf16_kernel<<<(int)(NQ / 4 + 255) / 256, 256, 0, stream>>>(Wq, Wqh, (int)(NQ / 4));
    tobf16_kernel<<<(int)(NQ / 4 + 255) / 256, 256, 0, stream>>>(Wo, Woh, (int)(NQ / 4));
    tobf16_kernel<<<(int)(NF / 4 + 255) / 256, 256, 0, stream>>>(W1, W1h, (int)(NF / 4));
    tobf16_kernel<<<(int)(NF / 4 + 255) / 256, 256, 0, stream>>>(W2, W2h, (int)(NF / 4));
    for (int l = 0; l < NLAYER_; ++l) {
        tobf16_kernel<<<(int)(NQl / 4 + 255) / 256, 256, 0, stream>>>(
            Wk + l * NQl, Wkvh + l * 2 * NQl, (int)(NQl / 4));
        tobf16_kernel<<<(int)(NQl / 4 + 255) / 256, 256, 0, stream>>>(
            Wv + l * NQl, Wkvh + l * 2 * NQl + NQl, (int)(NQl / 4));
    }

    // build X (fp32, persistent) and X2 (fp32 in Tb scratch, converted once)
    float* X2tmp = Tb;
    write_cls_kernel<<<(B_ * D_) / 256, 256, 0, stream>>>(cls, X, X2tmp);
    transpose_embed_kernel<<<dim3(L0_ / 32, D_ / 32, B_), dim3(32, 8), 0, stream>>>(embed1, X);
    transpose_embed_kernel<<<dim3(L0_ / 32, D_ / 32, B_), dim3(32, 8), 0, stream>>>(embed2, X2tmp);
    tobf16_kernel<<<(int)(SZ / 4 + 255) / 256, 256, 0, stream>>>(X, Xh, (int)(SZ / 4));
    tobf16_kernel<<<(int)(SZ / 4 + 255) / 256, 256, 0, stream>>>(X2tmp, X2h, (int)(SZ / 4));

    const int GM = (M_ + 127) / 128;         // 65
    const int g512  = GM * (512 / 64);       // 520
    const int g1024 = GM * (1024 / 64);      // 1040
    const int g2048 = GM * (2048 / 64);      // 2080
    const int gpad  = (B_ * H_ * DH_ * (LP_ - L_) + 255) / 256;
    const int gmerge = (M_ * 64 + 255) / 256;

    for (int l = 0; l < NLAYER_; ++l) {
        const size_t oQ = (size_t)l * NQl;
        const size_t oF = (size_t)l * DFF_ * D_;

        gemm_mfma_kernel<false, 2><<<g512, 256, 0, stream>>>(
            Xh, Wqh + oQ, bq + l * D_, nullptr, Qbh, M_, D_, D_, QSCALE_);
        gemm_kv_kernel<<<g1024, 256, 0, stream>>>(
            X2h, Wkvh + l * 2 * NQl, bk + l * D_, bv + l * D_, Kbh, Vtb);
        zero_vt_pad_kernel<<<gpad, 256, 0, stream>>>(Vtb);

        attn_mfma_kernel<<<NSPLIT_ * NQT_ * H_ * B_, 256, 0, stream>>>(
            Qbh, Kbh, Vtb, Opart, mlBuf);
        attn_merge_kernel<<<gmerge, 256, 0, stream>>>(Opart, mlBuf, Tbh);

        gemm_mfma_kernel<false, 0><<<g512, 256, 0, stream>>>(
            Tbh, Woh + oQ, bo + l * D_, WoOut, nullptr, M_, D_, D_, 1.f);

        add_ln_kernel<true><<<(M_ + 3) / 4, 256, 0, stream>>>(
            X, WoOut, ln1g + l * D_, ln1b + l * D_, X, Xh);

        gemm_mfma_kernel<true, 2><<<g2048, 256, 0, stream>>>(
            Xh, W1h + oF, b1 + l * DFF_, nullptr, Hbh, M_, DFF_, D_, 1.f);
        gemm_mfma_kernel<false, 0><<<g512, 256, 0, stream>>>(
            Hbh, W2h + oF, b2 + l * D_, Tb, nullptr, M_, D_, DFF_, 1.f);

        if (l == NLAYER_ - 1) {
            add_ln_kernel<false><<<(M_ + 3) / 4, 256, 0, stream>>>(
                X, Tb, ln2g + l * D_, ln2b + l * D_, (float*)d_out, nullptr);
        } else {
            add_ln_kernel<true><<<(M_ + 3) / 4, 256, 0, stream>>>(
                X, Tb, ln2g + l * D_, ln2b + l * D_, X, Xh);
        }
    }
}